// Round 9
// baseline (299.344 us; speedup 1.0000x reference)
//
#include <hip/hip_runtime.h>

#define N_NODES 50000
#define N_EDGES 800000
#define IN_DIM 64
#define HID_DIM 128
#define OUT_DIM 10
#define N_GRAPHS 64

#define SCAN_BLOCKS ((N_NODES + 255) / 256)   // 196
#define FILL_PASSES 16
#define FILL_RANGE ((N_NODES + FILL_PASSES - 1) / FILL_PASSES)   // 3125

typedef short bf16x8 __attribute__((ext_vector_type(8)));
typedef float f32x4  __attribute__((ext_vector_type(4)));

// ---- bf16 pack/unpack helpers (RNE pack; unpack = shift/mask) ----
__device__ __forceinline__ unsigned bf16pack2(float a, float b) {
    unsigned ua = __float_as_uint(a), ub = __float_as_uint(b);
    ua = (ua + 0x7FFFu + ((ua >> 16) & 1u)) >> 16;
    ub = (ub + 0x7FFFu + ((ub >> 16) & 1u)) >> 16;
    return ua | (ub << 16);
}
__device__ __forceinline__ unsigned short bf16r(float v) {
    unsigned u = __float_as_uint(v);
    u = (u + 0x7FFFu + ((u >> 16) & 1u)) >> 16;
    return (unsigned short)u;
}
__device__ __forceinline__ float bf16lo(unsigned u) { return __uint_as_float(u << 16); }
__device__ __forceinline__ float bf16hi(unsigned u) { return __uint_as_float(u & 0xFFFF0000u); }

// ---------------- degree ----------------

__global__ void k_degcount(const int* __restrict__ dst, int* __restrict__ deg) {
    int e = blockIdx.x * blockDim.x + threadIdx.x;
    if (e < N_EDGES) atomicAdd(&deg[dst[e]], 1);
}

// ---------------- 3-phase parallel scan of deg -> row_ptr (+bounds fused) ----------------

__global__ __launch_bounds__(256) void k_scan1(const int* __restrict__ deg,
                                               int* __restrict__ bsum,
                                               float* __restrict__ dinv,
                                               const int* __restrict__ batch,
                                               int* __restrict__ gstart) {
    __shared__ int red[256];
    int i = blockIdx.x * 256 + threadIdx.x;
    int d = (i < N_NODES) ? deg[i] : 0;
    if (i < N_NODES) {
        dinv[i] = rsqrtf((float)(d + 1));
        int b = batch[i];
        if (i == 0) {
            for (int g = 0; g <= b; g++) gstart[g] = 0;
        } else {
            int a = batch[i - 1];
            for (int g = a + 1; g <= b; g++) gstart[g] = i;
        }
        if (i == N_NODES - 1) {
            for (int g = b + 1; g <= N_GRAPHS; g++) gstart[g] = N_NODES;
        }
    }
    red[threadIdx.x] = d;
    __syncthreads();
#pragma unroll
    for (int off = 128; off > 0; off >>= 1) {
        if (threadIdx.x < off) red[threadIdx.x] += red[threadIdx.x + off];
        __syncthreads();
    }
    if (threadIdx.x == 0) bsum[blockIdx.x] = red[0];
}

__global__ __launch_bounds__(256) void k_scan2(const int* __restrict__ bsum,
                                               int* __restrict__ boff) {
    __shared__ int s[256];
    int t = threadIdx.x;
    s[t] = (t < SCAN_BLOCKS) ? bsum[t] : 0;
    __syncthreads();
#pragma unroll
    for (int off = 1; off < 256; off <<= 1) {
        int v = (t >= off) ? s[t - off] : 0;
        __syncthreads();
        s[t] += v;
        __syncthreads();
    }
    if (t < SCAN_BLOCKS) boff[t] = (t > 0) ? s[t - 1] : 0;
}

__global__ __launch_bounds__(256) void k_scan3(const int* __restrict__ deg,
                                               const int* __restrict__ boff,
                                               int* __restrict__ row_ptr,
                                               int* __restrict__ cursor) {
    __shared__ int s[256];
    int t = threadIdx.x;
    int i = blockIdx.x * 256 + t;
    int d = (i < N_NODES) ? deg[i] : 0;
    s[t] = d;
    __syncthreads();
#pragma unroll
    for (int off = 1; off < 256; off <<= 1) {
        int v = (t >= off) ? s[t - off] : 0;
        __syncthreads();
        s[t] += v;
        __syncthreads();
    }
    if (i < N_NODES) {
        int excl = boff[blockIdx.x] + s[t] - d;
        row_ptr[i] = excl;
        cursor[i] = excl;
    }
    if (i == 0) row_ptr[N_NODES] = N_EDGES;
}

// ---------------- CSR fill, dst-range partitioned for write locality ----------------
// Each thread caches 4 edges in registers (int4 coalesced read), then loops 16
// passes over 3125-node dst windows; col writes within a pass hit a 200 KB
// window so L2 lines accumulate ~16 entries before writeback.

__global__ __launch_bounds__(256) void k_fill(const int* __restrict__ src,
                                              const int* __restrict__ dst,
                                              int* __restrict__ cursor,
                                              int* __restrict__ col) {
    int t4 = blockIdx.x * 256 + threadIdx.x;     // grid: 782 blocks; N_EDGES/4 = 200000
    if (t4 >= N_EDGES / 4) return;
    int4 d4 = ((const int4*)dst)[t4];
    int4 s4 = ((const int4*)src)[t4];
    int d[4] = {d4.x, d4.y, d4.z, d4.w};
    int s[4] = {s4.x, s4.y, s4.z, s4.w};
    for (int p = 0; p < FILL_PASSES; p++) {
        int lo = p * FILL_RANGE, hi = lo + FILL_RANGE;
#pragma unroll
        for (int k = 0; k < 4; k++) {
            if (d[k] >= lo && d[k] < hi) {
                int pos = atomicAdd(&cursor[d[k]], 1);
                col[pos] = s[k];
            }
        }
    }
}

// ---------------- weight fp32 -> bf16 pack (w1: 128x64, w2: 128x128) ----------------

__global__ __launch_bounds__(256) void k_wpack(const float* __restrict__ w1,
                                               const float* __restrict__ w2,
                                               unsigned* __restrict__ w1b,
                                               unsigned* __restrict__ w2b) {
    int i = blockIdx.x * 256 + threadIdx.x;   // exact grid: 48 blocks = 12288 = 4096 + 8192
    if (i < 4096) {
        float2 v = ((const float2*)w1)[i];
        w1b[i] = bf16pack2(v.x, v.y);
    } else {
        int j = i - 4096;
        float2 v = ((const float2*)w2)[j];
        w2b[j] = bf16pack2(v.x, v.y);
    }
}

// ---------------- x pre-scale + bf16 pack: xs[m] = bf16(dinv[m] * x[m]) ----------------

__global__ __launch_bounds__(256) void k_xscale(const float* __restrict__ x,
                                                const float* __restrict__ dinv,
                                                unsigned* __restrict__ xs) {
    int i = blockIdx.x * 256 + threadIdx.x;   // exact grid: N_NODES*32
    int m = i >> 5;
    float dm = dinv[m];
    float2 v = ((const float2*)x)[i];
    xs[i] = bf16pack2(dm * v.x, dm * v.y);
}

// ---------------- gather64 (bf16 in, bf16 out): agg[d] = bf16(dinv[d]*(xs[d]+sum xs[s])) ----------------

__global__ __launch_bounds__(256) void k_gather64(const unsigned* __restrict__ xs,
                                                  const int* __restrict__ row_ptr,
                                                  const int* __restrict__ col,
                                                  const float* __restrict__ dinv,
                                                  unsigned* __restrict__ agg) {
    const int g = blockIdx.x * 8 + (threadIdx.x >> 5);   // grid 6250*8 = 50000 exact
    const int c = threadIdx.x & 31;

    unsigned v = xs[(size_t)g * 32 + c];
    float ax = bf16lo(v), ay = bf16hi(v);

    const int beg = row_ptr[g], end = row_ptr[g + 1];
    for (int j = beg; j < end; j += 8) {
        int   idx[8];
        float wt[8];
#pragma unroll
        for (int k = 0; k < 8; k++) {
            int jj = j + k;
            bool in = jj < end;
            idx[k] = in ? jj : (end - 1);
            wt[k] = in ? 1.f : 0.f;
        }
        int s[8];
#pragma unroll
        for (int k = 0; k < 8; k++) s[k] = col[idx[k]];
        unsigned u[8];
#pragma unroll
        for (int k = 0; k < 8; k++) u[k] = xs[(size_t)s[k] * 32 + c];
#pragma unroll
        for (int k = 0; k < 8; k++) {
            ax = fmaf(wt[k], bf16lo(u[k]), ax);
            ay = fmaf(wt[k], bf16hi(u[k]), ay);
        }
    }
    float dm = dinv[g];
    agg[(size_t)g * 32 + c] = bf16pack2(dm * ax, dm * ay);
}

// ---------------- gather128 (bf16 rows): out[d] = relu(dinv[d]*(ts[d]+sum ts[s]) + b) ----------------

__global__ __launch_bounds__(256) void k_gather128(const uint2* __restrict__ ts,
                                                   const int* __restrict__ row_ptr,
                                                   const int* __restrict__ col,
                                                   const float* __restrict__ dinv,
                                                   const float* __restrict__ bias,
                                                   float* __restrict__ out) {
    const int g = blockIdx.x * 8 + (threadIdx.x >> 5);   // grid 6250*8 = 50000 exact
    const int c = threadIdx.x & 31;

    uint2 v = ts[(size_t)g * 32 + c];
    float ax = bf16lo(v.x), ay = bf16hi(v.x), az = bf16lo(v.y), aw = bf16hi(v.y);

    const int beg = row_ptr[g], end = row_ptr[g + 1];
    for (int j = beg; j < end; j += 8) {
        int   idx[8];
        float wt[8];
#pragma unroll
        for (int k = 0; k < 8; k++) {
            int jj = j + k;
            bool in = jj < end;
            idx[k] = in ? jj : (end - 1);
            wt[k] = in ? 1.f : 0.f;
        }
        int s[8];
#pragma unroll
        for (int k = 0; k < 8; k++) s[k] = col[idx[k]];
        uint2 u[8];
#pragma unroll
        for (int k = 0; k < 8; k++) u[k] = ts[(size_t)s[k] * 32 + c];
#pragma unroll
        for (int k = 0; k < 8; k++) {
            ax = fmaf(wt[k], bf16lo(u[k].x), ax);
            ay = fmaf(wt[k], bf16hi(u[k].x), ay);
            az = fmaf(wt[k], bf16lo(u[k].y), az);
            aw = fmaf(wt[k], bf16hi(u[k].y), aw);
        }
    }
    float dm = dinv[g];
    float4 b = ((const float4*)bias)[c];
    float4 o;
    o.x = fmaxf(fmaf(dm, ax, b.x), 0.f);
    o.y = fmaxf(fmaf(dm, ay, b.y), 0.f);
    o.z = fmaxf(fmaf(dm, az, b.z), 0.f);
    o.w = fmaxf(fmaf(dm, aw, b.w), 0.f);
    ((float4*)out)[(size_t)g * 32 + c] = o;
}

// ---------------- MFMA bf16 GEMM: D[m][n] = sum_k X[m][k]*W[n][k]  (N=128) ----------------
// MODE 1: out = bf16(relu(acc + bias[n]));  MODE 2: out = bf16(dinv[m]*acc)

template<int K, int MODE>
__global__ __launch_bounds__(256) void k_gemm_mfma(const unsigned* __restrict__ Xb,
                                                   const unsigned* __restrict__ Wb,
                                                   const float* __restrict__ bias,
                                                   const float* __restrict__ dinv,
                                                   unsigned short* __restrict__ Ob) {
    constexpr int KU  = K / 2;
    constexpr int SP  = K + 8;
    constexpr int SPU = SP / 2;
    __shared__ __align__(16) unsigned As_u[64 * SPU];
    __shared__ __align__(16) unsigned Bs_u[128 * SPU];

    const int tid = threadIdx.x;
    const int bm = blockIdx.x * 64;

    for (int i = tid; i < 64 * KU; i += 256) {
        int r = i / KU, c = i % KU;
        int m = bm + r;
        As_u[r * SPU + c] = (m < N_NODES) ? Xb[(size_t)m * KU + c] : 0u;
    }
    for (int i = tid; i < 128 * KU; i += 256) {
        int r = i / KU, c = i % KU;
        Bs_u[r * SPU + c] = Wb[r * KU + c];
    }
    __syncthreads();

    const int wv = tid >> 6;
    const int lane = tid & 63;
    const int lr = lane & 15;
    const int q = lane >> 4;

    f32x4 acc[8];
#pragma unroll
    for (int nt = 0; nt < 8; nt++) acc[nt] = (f32x4){0.f, 0.f, 0.f, 0.f};

    const short* As_s = (const short*)As_u;
    const short* Bs_s = (const short*)Bs_u;
#pragma unroll
    for (int k0 = 0; k0 < K; k0 += 32) {
        bf16x8 a = *(const bf16x8*)(As_s + (wv * 16 + lr) * SP + k0 + q * 8);
#pragma unroll
        for (int nt = 0; nt < 8; nt++) {
            bf16x8 b = *(const bf16x8*)(Bs_s + (nt * 16 + lr) * SP + k0 + q * 8);
            acc[nt] = __builtin_amdgcn_mfma_f32_16x16x32_bf16(a, b, acc[nt], 0, 0, 0);
        }
    }

#pragma unroll
    for (int nt = 0; nt < 8; nt++) {
        int cN = nt * 16 + lr;
        float bv = (MODE == 1) ? bias[cN] : 0.f;
#pragma unroll
        for (int i = 0; i < 4; i++) {
            int m = bm + wv * 16 + q * 4 + i;
            if (m < N_NODES) {
                float v = acc[nt][i];
                if (MODE == 1) v = fmaxf(v + bv, 0.f);
                else           v = dinv[m] * v;
                Ob[(size_t)m * HID_DIM + cN] = bf16r(v);
            }
        }
    }
}

// ---------------- fused mean-pool + FC head ----------------

__global__ __launch_bounds__(256) void k_pool_fc(const float* __restrict__ h,
                                                 const int* __restrict__ gstart,
                                                 const float* __restrict__ fcw,
                                                 const float* __restrict__ fcb,
                                                 float* __restrict__ out) {
    const int g = blockIdx.x;
    const int f = threadIdx.x & 127;
    const int s = threadIdx.x >> 7;        // 0 or 1
    const int beg = gstart[g], end = gstart[g + 1];

    float acc = 0.f;
#pragma unroll 4
    for (int m = beg + s; m < end; m += 2)
        acc += h[(size_t)m * HID_DIM + f];

    __shared__ float tmp[256];
    __shared__ float pool[HID_DIM];
    tmp[threadIdx.x] = acc;
    __syncthreads();
    if (s == 0) {
        float tot = tmp[f] + tmp[128 + f];
        float c = fmaxf((float)(end - beg), 1.f);
        pool[f] = tot / c;
    }
    __syncthreads();
    if (threadIdx.x < OUT_DIM) {
        float a = fcb[threadIdx.x];
#pragma unroll 8
        for (int k = 0; k < HID_DIM; k++)
            a = fmaf(pool[k], fcw[threadIdx.x * HID_DIM + k], a);
        out[g * OUT_DIM + threadIdx.x] = a;
    }
}

// ---------------- launch ----------------

extern "C" void kernel_launch(void* const* d_in, const int* in_sizes, int n_in,
                              void* d_out, int out_size, void* d_ws, size_t ws_size,
                              hipStream_t stream) {
    const float* x   = (const float*)d_in[0];
    const int*  eidx = (const int*)d_in[1];
    const int* batch = (const int*)d_in[2];
    const float* w1  = (const float*)d_in[3];
    const float* b1  = (const float*)d_in[4];
    const float* w2  = (const float*)d_in[5];
    const float* b2  = (const float*)d_in[6];
    const float* fcw = (const float*)d_in[7];
    const float* fcb = (const float*)d_in[8];
    float* out = (float*)d_out;
    const int* src = eidx;             // edge_index[0]
    const int* dst = eidx + N_EDGES;   // edge_index[1]

    char* w = (char*)d_ws;
    unsigned* xs   = (unsigned*)(w);                  // 6,400,000 B
    unsigned* aggb = (unsigned*)(w + 6400000);        // 6,400,000 B
    uint2*    ts2  = (uint2*)(w);                     // 12,800,000 B (reuse of region A)
    unsigned short* h1b = (unsigned short*)(w + 12800000);  // 12,800,000 B
    float* bufB    = (float*)(w + 25600000);          // 25,600,000 B (out2 fp32)
    int*   deg     = (int*)  (w + 51200000);          // 200,000 B
    int*   row_ptr = (int*)  (w + 51400000);          // 200,064 B
    int*   cursor  = (int*)  (w + 51600064);          // 200,000 B
    float* dinv    = (float*)(w + 51800064);          // 200,000 B
    int*   col     = (int*)  (w + 52000064);          // 3,200,000 B
    int*   gstart  = (int*)  (w + 55200064);          // 260 B
    int*   bsum    = (int*)  (w + 55200384);          // 1024 B
    int*   boff    = (int*)  (w + 55201408);          // 1024 B
    unsigned* w1b  = (unsigned*)(w + 55202432);       // 16,384 B
    unsigned* w2b  = (unsigned*)(w + 55218816);       // 32,768 B

    dim3 b256(256);

    // CSR build (graph static across both layers) + graph boundaries + weight pack
    hipMemsetAsync(deg, 0, N_NODES * sizeof(int), stream);
    k_degcount<<<dim3((N_EDGES + 255) / 256), b256, 0, stream>>>(dst, deg);
    k_wpack<<<dim3(48), b256, 0, stream>>>(w1, w2, w1b, w2b);
    k_scan1<<<dim3(SCAN_BLOCKS), b256, 0, stream>>>(deg, bsum, dinv, batch, gstart);
    k_scan2<<<dim3(1), b256, 0, stream>>>(bsum, boff);
    k_scan3<<<dim3(SCAN_BLOCKS), b256, 0, stream>>>(deg, boff, row_ptr, cursor);
    k_fill<<<dim3((N_EDGES / 4 + 255) / 256), b256, 0, stream>>>(src, dst, cursor, col);

    // layer 1 (aggregate-then-transform, all-bf16 payloads):
    k_xscale<<<dim3(N_NODES * 32 / 256), b256, 0, stream>>>(x, dinv, xs);
    k_gather64<<<dim3(N_NODES / 8), b256, 0, stream>>>(xs, row_ptr, col, dinv, aggb);
    k_gemm_mfma<IN_DIM, 1><<<dim3((N_NODES + 63) / 64), b256, 0, stream>>>(aggb, w1b, b1, dinv, h1b);

    // layer 2 (transform-then-aggregate):
    k_gemm_mfma<HID_DIM, 2><<<dim3((N_NODES + 63) / 64), b256, 0, stream>>>((const unsigned*)h1b, w2b, b1, dinv, (unsigned short*)ts2);
    k_gather128<<<dim3(N_NODES / 8), b256, 0, stream>>>(ts2, row_ptr, col, dinv, b2, bufB);

    // fused mean-pool + FC head
    k_pool_fc<<<dim3(N_GRAPHS), b256, 0, stream>>>(bufB, gstart, fcw, fcb, out);
}

// Round 10
// 264.136 us; speedup vs baseline: 1.1333x; 1.1333x over previous
//
#include <hip/hip_runtime.h>

#define N_NODES 50000
#define N_EDGES 800000
#define IN_DIM 64
#define HID_DIM 128
#define OUT_DIM 10
#define N_GRAPHS 64

#define SCAN_BLOCKS ((N_NODES + 255) / 256)   // 196
#define NBUCK ((N_NODES + 255) / 256)         // 196 coarse buckets of 256 nodes

typedef short bf16x8 __attribute__((ext_vector_type(8)));
typedef float f32x4  __attribute__((ext_vector_type(4)));

// ---- bf16 pack/unpack helpers (RNE pack; unpack = shift/mask) ----
__device__ __forceinline__ unsigned bf16pack2(float a, float b) {
    unsigned ua = __float_as_uint(a), ub = __float_as_uint(b);
    ua = (ua + 0x7FFFu + ((ua >> 16) & 1u)) >> 16;
    ub = (ub + 0x7FFFu + ((ub >> 16) & 1u)) >> 16;
    return ua | (ub << 16);
}
__device__ __forceinline__ unsigned short bf16r(float v) {
    unsigned u = __float_as_uint(v);
    u = (u + 0x7FFFu + ((u >> 16) & 1u)) >> 16;
    return (unsigned short)u;
}
__device__ __forceinline__ float bf16lo(unsigned u) { return __uint_as_float(u << 16); }
__device__ __forceinline__ float bf16hi(unsigned u) { return __uint_as_float(u & 0xFFFF0000u); }

// ---------------- degree ----------------

__global__ void k_degcount(const int* __restrict__ dst, int* __restrict__ deg) {
    int e = blockIdx.x * blockDim.x + threadIdx.x;
    if (e < N_EDGES) atomicAdd(&deg[dst[e]], 1);
}

// ---------------- 3-phase parallel scan of deg -> row_ptr (+bounds fused) ----------------

__global__ __launch_bounds__(256) void k_scan1(const int* __restrict__ deg,
                                               int* __restrict__ bsum,
                                               float* __restrict__ dinv,
                                               const int* __restrict__ batch,
                                               int* __restrict__ gstart) {
    __shared__ int red[256];
    int i = blockIdx.x * 256 + threadIdx.x;
    int d = (i < N_NODES) ? deg[i] : 0;
    if (i < N_NODES) {
        dinv[i] = rsqrtf((float)(d + 1));
        int b = batch[i];
        if (i == 0) {
            for (int g = 0; g <= b; g++) gstart[g] = 0;
        } else {
            int a = batch[i - 1];
            for (int g = a + 1; g <= b; g++) gstart[g] = i;
        }
        if (i == N_NODES - 1) {
            for (int g = b + 1; g <= N_GRAPHS; g++) gstart[g] = N_NODES;
        }
    }
    red[threadIdx.x] = d;
    __syncthreads();
#pragma unroll
    for (int off = 128; off > 0; off >>= 1) {
        if (threadIdx.x < off) red[threadIdx.x] += red[threadIdx.x + off];
        __syncthreads();
    }
    if (threadIdx.x == 0) bsum[blockIdx.x] = red[0];
}

__global__ __launch_bounds__(256) void k_scan2(const int* __restrict__ bsum,
                                               int* __restrict__ boff) {
    __shared__ int s[256];
    int t = threadIdx.x;
    s[t] = (t < SCAN_BLOCKS) ? bsum[t] : 0;
    __syncthreads();
#pragma unroll
    for (int off = 1; off < 256; off <<= 1) {
        int v = (t >= off) ? s[t - off] : 0;
        __syncthreads();
        s[t] += v;
        __syncthreads();
    }
    if (t < SCAN_BLOCKS) boff[t] = (t > 0) ? s[t - 1] : 0;
}

// also seeds the coarse-bucket write cursors gcur[b] = row_ptr[b*256]
__global__ __launch_bounds__(256) void k_scan3(const int* __restrict__ deg,
                                               const int* __restrict__ boff,
                                               int* __restrict__ row_ptr,
                                               int* __restrict__ gcur) {
    __shared__ int s[256];
    int t = threadIdx.x;
    int i = blockIdx.x * 256 + t;
    int d = (i < N_NODES) ? deg[i] : 0;
    s[t] = d;
    __syncthreads();
#pragma unroll
    for (int off = 1; off < 256; off <<= 1) {
        int v = (t >= off) ? s[t - off] : 0;
        __syncthreads();
        s[t] += v;
        __syncthreads();
    }
    if (i < N_NODES) {
        int excl = boff[blockIdx.x] + s[t] - d;
        row_ptr[i] = excl;
        if ((i & 255) == 0) gcur[i >> 8] = excl;
    }
    if (i == 0) row_ptr[N_NODES] = N_EDGES;
}

// ---------------- CSR fill: two-level counting sort ----------------
// fill1: 196 blocks x 4096 edges; LDS histogram by dst>>8; reserve contiguous
// runs per (block,bucket) via one global atomic each; write packed
// (src | fine_dst<<16) u32 runs into ebuf (coalesced ~21-entry runs).

__global__ __launch_bounds__(256) void k_fill1(const int* __restrict__ src,
                                               const int* __restrict__ dst,
                                               int* __restrict__ gcur,
                                               unsigned* __restrict__ ebuf) {
    __shared__ int hcnt[NBUCK], hbase[NBUCK], hrun[NBUCK];
    const int tid = threadIdx.x;
    for (int f = tid; f < NBUCK; f += 256) { hcnt[f] = 0; hrun[f] = 0; }
    __syncthreads();

    int4 s4[4], d4[4];
    bool val[4];
    const int base4 = blockIdx.x * 1024 + tid;   // int4 index; grid 196 blocks
#pragma unroll
    for (int r = 0; r < 4; r++) {
        int i4 = base4 + r * 256;
        val[r] = i4 < N_EDGES / 4;
        if (val[r]) { s4[r] = ((const int4*)src)[i4]; d4[r] = ((const int4*)dst)[i4]; }
    }
#pragma unroll
    for (int r = 0; r < 4; r++) if (val[r]) {
        int dd[4] = {d4[r].x, d4[r].y, d4[r].z, d4[r].w};
#pragma unroll
        for (int k = 0; k < 4; k++) atomicAdd(&hcnt[dd[k] >> 8], 1);
    }
    __syncthreads();
    for (int f = tid; f < NBUCK; f += 256)
        hbase[f] = atomicAdd(&gcur[f], hcnt[f]);
    __syncthreads();
#pragma unroll
    for (int r = 0; r < 4; r++) if (val[r]) {
        int dd[4] = {d4[r].x, d4[r].y, d4[r].z, d4[r].w};
        int ss[4] = {s4[r].x, s4[r].y, s4[r].z, s4[r].w};
#pragma unroll
        for (int k = 0; k < 4; k++) {
            int b = dd[k] >> 8;
            int pos = hbase[b] + atomicAdd(&hrun[b], 1);
            ebuf[pos] = (unsigned)ss[k] | ((unsigned)(dd[k] & 255) << 16);
        }
    }
}

// fill2: one block per coarse bucket; stream bucket's edge range (coalesced),
// LDS cursor per node, scatter u16 src into the bucket's private col window.
__global__ __launch_bounds__(256) void k_fill2(const unsigned* __restrict__ ebuf,
                                               const int* __restrict__ row_ptr,
                                               unsigned short* __restrict__ col) {
    __shared__ int cur[256];
    const int b = blockIdx.x;       // 196 blocks
    const int f = threadIdx.x;
    int node = b * 256 + f;
    cur[f] = (node < N_NODES) ? row_ptr[node] : 0;
    int lo = b * 256; if (lo > N_NODES) lo = N_NODES;
    int hi = (b + 1) * 256; if (hi > N_NODES) hi = N_NODES;
    const int start = row_ptr[lo], endr = row_ptr[hi];
    __syncthreads();
    for (int i = start + f; i < endr; i += 256) {
        unsigned e = ebuf[i];
        int fine = (e >> 16) & 0xFF;
        int pos = atomicAdd(&cur[fine], 1);
        col[pos] = (unsigned short)(e & 0xFFFFu);
    }
}

// ---------------- weight fp32 -> bf16 pack (w1: 128x64, w2: 128x128) ----------------

__global__ __launch_bounds__(256) void k_wpack(const float* __restrict__ w1,
                                               const float* __restrict__ w2,
                                               unsigned* __restrict__ w1b,
                                               unsigned* __restrict__ w2b) {
    int i = blockIdx.x * 256 + threadIdx.x;   // exact grid: 48 blocks
    if (i < 4096) {
        float2 v = ((const float2*)w1)[i];
        w1b[i] = bf16pack2(v.x, v.y);
    } else {
        int j = i - 4096;
        float2 v = ((const float2*)w2)[j];
        w2b[j] = bf16pack2(v.x, v.y);
    }
}

// ---------------- x pre-scale + bf16 pack: xs[m] = bf16(dinv[m] * x[m]) ----------------

__global__ __launch_bounds__(256) void k_xscale(const float* __restrict__ x,
                                                const float* __restrict__ dinv,
                                                unsigned* __restrict__ xs) {
    int i = blockIdx.x * 256 + threadIdx.x;   // exact grid: N_NODES*32
    int m = i >> 5;
    float dm = dinv[m];
    float2 v = ((const float2*)x)[i];
    xs[i] = bf16pack2(dm * v.x, dm * v.y);
}

// ---------------- gather64 (bf16 in, bf16 out): agg[d] = bf16(dinv[d]*(xs[d]+sum xs[s])) ----------------

__global__ __launch_bounds__(256) void k_gather64(const unsigned* __restrict__ xs,
                                                  const int* __restrict__ row_ptr,
                                                  const unsigned short* __restrict__ col,
                                                  const float* __restrict__ dinv,
                                                  unsigned* __restrict__ agg) {
    const int g = blockIdx.x * 8 + (threadIdx.x >> 5);   // grid 6250*8 = 50000 exact
    const int c = threadIdx.x & 31;

    unsigned v = xs[(size_t)g * 32 + c];
    float ax = bf16lo(v), ay = bf16hi(v);

    const int beg = row_ptr[g], end = row_ptr[g + 1];
    for (int j = beg; j < end; j += 8) {
        int   idx[8];
        float wt[8];
#pragma unroll
        for (int k = 0; k < 8; k++) {
            int jj = j + k;
            bool in = jj < end;
            idx[k] = in ? jj : (end - 1);
            wt[k] = in ? 1.f : 0.f;
        }
        int s[8];
#pragma unroll
        for (int k = 0; k < 8; k++) s[k] = col[idx[k]];
        unsigned u[8];
#pragma unroll
        for (int k = 0; k < 8; k++) u[k] = xs[(size_t)s[k] * 32 + c];
#pragma unroll
        for (int k = 0; k < 8; k++) {
            ax = fmaf(wt[k], bf16lo(u[k]), ax);
            ay = fmaf(wt[k], bf16hi(u[k]), ay);
        }
    }
    float dm = dinv[g];
    agg[(size_t)g * 32 + c] = bf16pack2(dm * ax, dm * ay);
}

// ---------------- gather128 (bf16 rows): out[d] = relu(dinv[d]*(ts[d]+sum ts[s]) + b) ----------------

__global__ __launch_bounds__(256) void k_gather128(const uint2* __restrict__ ts,
                                                   const int* __restrict__ row_ptr,
                                                   const unsigned short* __restrict__ col,
                                                   const float* __restrict__ dinv,
                                                   const float* __restrict__ bias,
                                                   float* __restrict__ out) {
    const int g = blockIdx.x * 8 + (threadIdx.x >> 5);   // grid 6250*8 = 50000 exact
    const int c = threadIdx.x & 31;

    uint2 v = ts[(size_t)g * 32 + c];
    float ax = bf16lo(v.x), ay = bf16hi(v.x), az = bf16lo(v.y), aw = bf16hi(v.y);

    const int beg = row_ptr[g], end = row_ptr[g + 1];
    for (int j = beg; j < end; j += 8) {
        int   idx[8];
        float wt[8];
#pragma unroll
        for (int k = 0; k < 8; k++) {
            int jj = j + k;
            bool in = jj < end;
            idx[k] = in ? jj : (end - 1);
            wt[k] = in ? 1.f : 0.f;
        }
        int s[8];
#pragma unroll
        for (int k = 0; k < 8; k++) s[k] = col[idx[k]];
        uint2 u[8];
#pragma unroll
        for (int k = 0; k < 8; k++) u[k] = ts[(size_t)s[k] * 32 + c];
#pragma unroll
        for (int k = 0; k < 8; k++) {
            ax = fmaf(wt[k], bf16lo(u[k].x), ax);
            ay = fmaf(wt[k], bf16hi(u[k].x), ay);
            az = fmaf(wt[k], bf16lo(u[k].y), az);
            aw = fmaf(wt[k], bf16hi(u[k].y), aw);
        }
    }
    float dm = dinv[g];
    float4 b = ((const float4*)bias)[c];
    float4 o;
    o.x = fmaxf(fmaf(dm, ax, b.x), 0.f);
    o.y = fmaxf(fmaf(dm, ay, b.y), 0.f);
    o.z = fmaxf(fmaf(dm, az, b.z), 0.f);
    o.w = fmaxf(fmaf(dm, aw, b.w), 0.f);
    ((float4*)out)[(size_t)g * 32 + c] = o;
}

// ---------------- MFMA bf16 GEMM: D[m][n] = sum_k X[m][k]*W[n][k]  (N=128) ----------------
// MODE 1: out = bf16(relu(acc + bias[n]));  MODE 2: out = bf16(dinv[m]*acc)

template<int K, int MODE>
__global__ __launch_bounds__(256) void k_gemm_mfma(const unsigned* __restrict__ Xb,
                                                   const unsigned* __restrict__ Wb,
                                                   const float* __restrict__ bias,
                                                   const float* __restrict__ dinv,
                                                   unsigned short* __restrict__ Ob) {
    constexpr int KU  = K / 2;
    constexpr int SP  = K + 8;
    constexpr int SPU = SP / 2;
    __shared__ __align__(16) unsigned As_u[64 * SPU];
    __shared__ __align__(16) unsigned Bs_u[128 * SPU];

    const int tid = threadIdx.x;
    const int bm = blockIdx.x * 64;

    for (int i = tid; i < 64 * KU; i += 256) {
        int r = i / KU, c = i % KU;
        int m = bm + r;
        As_u[r * SPU + c] = (m < N_NODES) ? Xb[(size_t)m * KU + c] : 0u;
    }
    for (int i = tid; i < 128 * KU; i += 256) {
        int r = i / KU, c = i % KU;
        Bs_u[r * SPU + c] = Wb[r * KU + c];
    }
    __syncthreads();

    const int wv = tid >> 6;
    const int lane = tid & 63;
    const int lr = lane & 15;
    const int q = lane >> 4;

    f32x4 acc[8];
#pragma unroll
    for (int nt = 0; nt < 8; nt++) acc[nt] = (f32x4){0.f, 0.f, 0.f, 0.f};

    const short* As_s = (const short*)As_u;
    const short* Bs_s = (const short*)Bs_u;
#pragma unroll
    for (int k0 = 0; k0 < K; k0 += 32) {
        bf16x8 a = *(const bf16x8*)(As_s + (wv * 16 + lr) * SP + k0 + q * 8);
#pragma unroll
        for (int nt = 0; nt < 8; nt++) {
            bf16x8 b = *(const bf16x8*)(Bs_s + (nt * 16 + lr) * SP + k0 + q * 8);
            acc[nt] = __builtin_amdgcn_mfma_f32_16x16x32_bf16(a, b, acc[nt], 0, 0, 0);
        }
    }

#pragma unroll
    for (int nt = 0; nt < 8; nt++) {
        int cN = nt * 16 + lr;
        float bv = (MODE == 1) ? bias[cN] : 0.f;
#pragma unroll
        for (int i = 0; i < 4; i++) {
            int m = bm + wv * 16 + q * 4 + i;
            if (m < N_NODES) {
                float v = acc[nt][i];
                if (MODE == 1) v = fmaxf(v + bv, 0.f);
                else           v = dinv[m] * v;
                Ob[(size_t)m * HID_DIM + cN] = bf16r(v);
            }
        }
    }
}

// ---------------- fused mean-pool + FC head ----------------

__global__ __launch_bounds__(256) void k_pool_fc(const float* __restrict__ h,
                                                 const int* __restrict__ gstart,
                                                 const float* __restrict__ fcw,
                                                 const float* __restrict__ fcb,
                                                 float* __restrict__ out) {
    const int g = blockIdx.x;
    const int f = threadIdx.x & 127;
    const int s = threadIdx.x >> 7;        // 0 or 1
    const int beg = gstart[g], end = gstart[g + 1];

    float acc = 0.f;
#pragma unroll 4
    for (int m = beg + s; m < end; m += 2)
        acc += h[(size_t)m * HID_DIM + f];

    __shared__ float tmp[256];
    __shared__ float pool[HID_DIM];
    tmp[threadIdx.x] = acc;
    __syncthreads();
    if (s == 0) {
        float tot = tmp[f] + tmp[128 + f];
        float c = fmaxf((float)(end - beg), 1.f);
        pool[f] = tot / c;
    }
    __syncthreads();
    if (threadIdx.x < OUT_DIM) {
        float a = fcb[threadIdx.x];
#pragma unroll 8
        for (int k = 0; k < HID_DIM; k++)
            a = fmaf(pool[k], fcw[threadIdx.x * HID_DIM + k], a);
        out[g * OUT_DIM + threadIdx.x] = a;
    }
}

// ---------------- launch ----------------

extern "C" void kernel_launch(void* const* d_in, const int* in_sizes, int n_in,
                              void* d_out, int out_size, void* d_ws, size_t ws_size,
                              hipStream_t stream) {
    const float* x   = (const float*)d_in[0];
    const int*  eidx = (const int*)d_in[1];
    const int* batch = (const int*)d_in[2];
    const float* w1  = (const float*)d_in[3];
    const float* b1  = (const float*)d_in[4];
    const float* w2  = (const float*)d_in[5];
    const float* b2  = (const float*)d_in[6];
    const float* fcw = (const float*)d_in[7];
    const float* fcb = (const float*)d_in[8];
    float* out = (float*)d_out;
    const int* src = eidx;             // edge_index[0]
    const int* dst = eidx + N_EDGES;   // edge_index[1]

    char* w = (char*)d_ws;
    unsigned* xs   = (unsigned*)(w);                  // 6,400,000 B
    unsigned* aggb = (unsigned*)(w + 6400000);        // 6,400,000 B
    uint2*    ts2  = (uint2*)(w);                     // 12,800,000 B (reuse of region A)
    unsigned short* h1b = (unsigned short*)(w + 12800000);  // 12,800,000 B
    float* bufB    = (float*)(w + 25600000);          // 25,600,000 B (out2 fp32, late)
    unsigned* ebuf = (unsigned*)(w + 25600000);       // 3,200,000 B  (CSR build, early — reuses bufB)
    int*   deg     = (int*)  (w + 51200000);          // 200,000 B
    int*   row_ptr = (int*)  (w + 51400000);          // 200,064 B
    int*   gcur    = (int*)  (w + 51600064);          // 1,024 B (196 ints)
    float* dinv    = (float*)(w + 51800064);          // 200,000 B
    unsigned short* col = (unsigned short*)(w + 52000064);  // 1,600,000 B (u16)
    int*   gstart  = (int*)  (w + 55200064);          // 260 B
    int*   bsum    = (int*)  (w + 55200384);          // 1024 B
    int*   boff    = (int*)  (w + 55201408);          // 1024 B
    unsigned* w1b  = (unsigned*)(w + 55202432);       // 16,384 B
    unsigned* w2b  = (unsigned*)(w + 55218816);       // 32,768 B

    dim3 b256(256);

    // CSR build (graph static across both layers) + graph boundaries + weight pack
    hipMemsetAsync(deg, 0, N_NODES * sizeof(int), stream);
    k_degcount<<<dim3((N_EDGES + 255) / 256), b256, 0, stream>>>(dst, deg);
    k_wpack<<<dim3(48), b256, 0, stream>>>(w1, w2, w1b, w2b);
    k_scan1<<<dim3(SCAN_BLOCKS), b256, 0, stream>>>(deg, bsum, dinv, batch, gstart);
    k_scan2<<<dim3(1), b256, 0, stream>>>(bsum, boff);
    k_scan3<<<dim3(SCAN_BLOCKS), b256, 0, stream>>>(deg, boff, row_ptr, gcur);
    k_fill1<<<dim3((N_EDGES / 4 + 1023) / 1024), b256, 0, stream>>>(src, dst, gcur, ebuf);
    k_fill2<<<dim3(NBUCK), b256, 0, stream>>>(ebuf, row_ptr, col);

    // layer 1 (aggregate-then-transform, all-bf16 payloads):
    k_xscale<<<dim3(N_NODES * 32 / 256), b256, 0, stream>>>(x, dinv, xs);
    k_gather64<<<dim3(N_NODES / 8), b256, 0, stream>>>(xs, row_ptr, col, dinv, aggb);
    k_gemm_mfma<IN_DIM, 1><<<dim3((N_NODES + 63) / 64), b256, 0, stream>>>(aggb, w1b, b1, dinv, h1b);

    // layer 2 (transform-then-aggregate):
    k_gemm_mfma<HID_DIM, 2><<<dim3((N_NODES + 63) / 64), b256, 0, stream>>>((const unsigned*)h1b, w2b, b1, dinv, (unsigned short*)ts2);
    k_gather128<<<dim3(N_NODES / 8), b256, 0, stream>>>(ts2, row_ptr, col, dinv, b2, bufB);

    // fused mean-pool + FC head
    k_pool_fc<<<dim3(N_GRAPHS), b256, 0, stream>>>(bufB, gstart, fcw, fcb, out);
}

// Round 11
// 241.428 us; speedup vs baseline: 1.2399x; 1.0941x over previous
//
#include <hip/hip_runtime.h>

#define N_NODES 50000
#define N_EDGES 800000
#define IN_DIM 64
#define HID_DIM 128
#define OUT_DIM 10
#define N_GRAPHS 64

#define NBUCK ((N_NODES + 255) / 256)         // 196 coarse buckets of 256 nodes

typedef short bf16x8 __attribute__((ext_vector_type(8)));
typedef float f32x4  __attribute__((ext_vector_type(4)));

// ---- bf16 pack/unpack helpers (RNE pack; unpack = shift/mask) ----
__device__ __forceinline__ unsigned bf16pack2(float a, float b) {
    unsigned ua = __float_as_uint(a), ub = __float_as_uint(b);
    ua = (ua + 0x7FFFu + ((ua >> 16) & 1u)) >> 16;
    ub = (ub + 0x7FFFu + ((ub >> 16) & 1u)) >> 16;
    return ua | (ub << 16);
}
__device__ __forceinline__ unsigned short bf16r(float v) {
    unsigned u = __float_as_uint(v);
    u = (u + 0x7FFFu + ((u >> 16) & 1u)) >> 16;
    return (unsigned short)u;
}
__device__ __forceinline__ float bf16lo(unsigned u) { return __uint_as_float(u << 16); }
__device__ __forceinline__ float bf16hi(unsigned u) { return __uint_as_float(u & 0xFFFF0000u); }

// ---------------- hist: per-block coarse histogram (no global atomics) ----------------
// + fused: graph bounds from sorted batch; weight fp32->bf16 pack (blocks 0..47)

__global__ __launch_bounds__(256) void k_hist(const int* __restrict__ dst,
                                              const int* __restrict__ batch,
                                              const float* __restrict__ w1,
                                              const float* __restrict__ w2,
                                              int* __restrict__ hpart,
                                              int* __restrict__ gstart,
                                              unsigned* __restrict__ w1b,
                                              unsigned* __restrict__ w2b) {
    __shared__ int cnt[NBUCK];
    const int tid = threadIdx.x;
    const int b = blockIdx.x;          // 196 blocks
    for (int f = tid; f < NBUCK; f += 256) cnt[f] = 0;
    __syncthreads();

    const int base4 = b * 1024 + tid;  // int4 index over dst
#pragma unroll
    for (int r = 0; r < 4; r++) {
        int i4 = base4 + r * 256;
        if (i4 < N_EDGES / 4) {
            int4 d4 = ((const int4*)dst)[i4];
            atomicAdd(&cnt[d4.x >> 8], 1);
            atomicAdd(&cnt[d4.y >> 8], 1);
            atomicAdd(&cnt[d4.z >> 8], 1);
            atomicAdd(&cnt[d4.w >> 8], 1);
        }
    }
    __syncthreads();
    for (int f = tid; f < NBUCK; f += 256) hpart[b * NBUCK + f] = cnt[f];

    // fused: graph boundaries (batch sorted)
    int node = b * 256 + tid;
    if (node < N_NODES) {
        int bb = batch[node];
        if (node == 0) {
            for (int g = 0; g <= bb; g++) gstart[g] = 0;
        } else {
            int a = batch[node - 1];
            for (int g = a + 1; g <= bb; g++) gstart[g] = node;
        }
        if (node == N_NODES - 1) {
            for (int g = bb + 1; g <= N_GRAPHS; g++) gstart[g] = N_NODES;
        }
    }

    // fused: weight pack (12288 float2 -> uint)
    int i = b * 256 + tid;
    if (i < 4096) {
        float2 v = ((const float2*)w1)[i];
        w1b[i] = bf16pack2(v.x, v.y);
    } else if (i < 12288) {
        int j = i - 4096;
        float2 v = ((const float2*)w2)[j];
        w2b[j] = bf16pack2(v.x, v.y);
    }
}

// ---------------- bscan: bucket totals + exclusive scan -> gbase, gcur ----------------

__global__ __launch_bounds__(256) void k_bscan(const int* __restrict__ hpart,
                                               int* __restrict__ gbase,
                                               int* __restrict__ gcur) {
    __shared__ int s[256];
    int t = threadIdx.x;
    int sum = 0;
    if (t < NBUCK)
        for (int blk = 0; blk < NBUCK; blk++) sum += hpart[blk * NBUCK + t];
    s[t] = (t < NBUCK) ? sum : 0;
    __syncthreads();
#pragma unroll
    for (int off = 1; off < 256; off <<= 1) {
        int v = (t >= off) ? s[t - off] : 0;
        __syncthreads();
        s[t] += v;
        __syncthreads();
    }
    if (t < NBUCK) {
        int ex = (t > 0) ? s[t - 1] : 0;
        gbase[t] = ex;
        gcur[t] = ex;
    }
    if (t == 0) gbase[NBUCK] = N_EDGES;
}

// ---------------- fill1: bucket edges into ebuf (coalesced runs) ----------------

__global__ __launch_bounds__(256) void k_fill1(const int* __restrict__ src,
                                               const int* __restrict__ dst,
                                               int* __restrict__ gcur,
                                               unsigned* __restrict__ ebuf) {
    __shared__ int hcnt[NBUCK], hbase[NBUCK], hrun[NBUCK];
    const int tid = threadIdx.x;
    for (int f = tid; f < NBUCK; f += 256) { hcnt[f] = 0; hrun[f] = 0; }
    __syncthreads();

    int4 s4[4], d4[4];
    bool val[4];
    const int base4 = blockIdx.x * 1024 + tid;   // grid 196 blocks
#pragma unroll
    for (int r = 0; r < 4; r++) {
        int i4 = base4 + r * 256;
        val[r] = i4 < N_EDGES / 4;
        if (val[r]) { s4[r] = ((const int4*)src)[i4]; d4[r] = ((const int4*)dst)[i4]; }
    }
#pragma unroll
    for (int r = 0; r < 4; r++) if (val[r]) {
        int dd[4] = {d4[r].x, d4[r].y, d4[r].z, d4[r].w};
#pragma unroll
        for (int k = 0; k < 4; k++) atomicAdd(&hcnt[dd[k] >> 8], 1);
    }
    __syncthreads();
    for (int f = tid; f < NBUCK; f += 256)
        hbase[f] = atomicAdd(&gcur[f], hcnt[f]);
    __syncthreads();
#pragma unroll
    for (int r = 0; r < 4; r++) if (val[r]) {
        int dd[4] = {d4[r].x, d4[r].y, d4[r].z, d4[r].w};
        int ss[4] = {s4[r].x, s4[r].y, s4[r].z, s4[r].w};
#pragma unroll
        for (int k = 0; k < 4; k++) {
            int b = dd[k] >> 8;
            int pos = hbase[b] + atomicAdd(&hrun[b], 1);
            ebuf[pos] = (unsigned)ss[k] | ((unsigned)(dd[k] & 255) << 16);
        }
    }
}

// ---------------- fill2: per-bucket fine sort + row_ptr + dinv + col + xs ----------------
// one block per bucket: LDS fine-histogram -> scan -> row_ptr/dinv; scatter u16 col;
// fused xscale: xs[m] = bf16(dinv[m] * x[m]) for the bucket's 256 nodes.

__global__ __launch_bounds__(256) void k_fill2(const unsigned* __restrict__ ebuf,
                                               const int* __restrict__ gbase,
                                               const float* __restrict__ x,
                                               int* __restrict__ row_ptr,
                                               float* __restrict__ dinv,
                                               unsigned short* __restrict__ col,
                                               unsigned* __restrict__ xs) {
    __shared__ int cnt[256], cur[256], s[256];
    __shared__ float dv[256];
    const int b = blockIdx.x;       // 196 blocks
    const int f = threadIdx.x;
    const int start = gbase[b], endr = gbase[b + 1];

    cnt[f] = 0;
    __syncthreads();
    for (int i = start + f; i < endr; i += 256)
        atomicAdd(&cnt[(ebuf[i] >> 16) & 0xFF], 1);
    __syncthreads();

    int d = cnt[f];
    s[f] = d;
    __syncthreads();
#pragma unroll
    for (int off = 1; off < 256; off <<= 1) {
        int v = (f >= off) ? s[f - off] : 0;
        __syncthreads();
        s[f] += v;
        __syncthreads();
    }
    int excl = start + s[f] - d;
    int node = b * 256 + f;
    if (node < N_NODES) {
        row_ptr[node] = excl;
        float dvv = rsqrtf((float)(d + 1));
        dinv[node] = dvv;
        dv[f] = dvv;
    }
    cur[f] = excl;
    if (b == 0 && f == 0) row_ptr[N_NODES] = N_EDGES;
    __syncthreads();

    for (int i = start + f; i < endr; i += 256) {
        unsigned e = ebuf[i];
        int pos = atomicAdd(&cur[(e >> 16) & 0xFF], 1);
        col[pos] = (unsigned short)(e & 0xFFFFu);
    }

    // fused xscale for this bucket's nodes
    const int lo = b * 256;
    for (int j = f; j < 256 * 32; j += 256) {
        int nl = j >> 5;
        int m = lo + nl;
        if (m < N_NODES) {
            int chunk = j & 31;
            float2 v = ((const float2*)x)[(size_t)m * 32 + chunk];
            float dm = dv[nl];
            xs[(size_t)m * 32 + chunk] = bf16pack2(dm * v.x, dm * v.y);
        }
    }
}

// ---------------- gather64 (bf16 in, bf16 out): agg[d] = bf16(dinv[d]*(xs[d]+sum xs[s])) ----------------

__global__ __launch_bounds__(256) void k_gather64(const unsigned* __restrict__ xs,
                                                  const int* __restrict__ row_ptr,
                                                  const unsigned short* __restrict__ col,
                                                  const float* __restrict__ dinv,
                                                  unsigned* __restrict__ agg) {
    const int g = blockIdx.x * 8 + (threadIdx.x >> 5);   // grid 6250*8 = 50000 exact
    const int c = threadIdx.x & 31;

    unsigned v = xs[(size_t)g * 32 + c];
    float ax = bf16lo(v), ay = bf16hi(v);

    const int beg = row_ptr[g], end = row_ptr[g + 1];
    for (int j = beg; j < end; j += 8) {
        int   idx[8];
        float wt[8];
#pragma unroll
        for (int k = 0; k < 8; k++) {
            int jj = j + k;
            bool in = jj < end;
            idx[k] = in ? jj : (end - 1);
            wt[k] = in ? 1.f : 0.f;
        }
        int s[8];
#pragma unroll
        for (int k = 0; k < 8; k++) s[k] = col[idx[k]];
        unsigned u[8];
#pragma unroll
        for (int k = 0; k < 8; k++) u[k] = xs[(size_t)s[k] * 32 + c];
#pragma unroll
        for (int k = 0; k < 8; k++) {
            ax = fmaf(wt[k], bf16lo(u[k]), ax);
            ay = fmaf(wt[k], bf16hi(u[k]), ay);
        }
    }
    float dm = dinv[g];
    agg[(size_t)g * 32 + c] = bf16pack2(dm * ax, dm * ay);
}

// ---------------- gather128 (bf16 rows): out[d] = relu(dinv[d]*(ts[d]+sum ts[s]) + b) ----------------

__global__ __launch_bounds__(256) void k_gather128(const uint2* __restrict__ ts,
                                                   const int* __restrict__ row_ptr,
                                                   const unsigned short* __restrict__ col,
                                                   const float* __restrict__ dinv,
                                                   const float* __restrict__ bias,
                                                   float* __restrict__ out) {
    const int g = blockIdx.x * 8 + (threadIdx.x >> 5);   // grid 6250*8 = 50000 exact
    const int c = threadIdx.x & 31;

    uint2 v = ts[(size_t)g * 32 + c];
    float ax = bf16lo(v.x), ay = bf16hi(v.x), az = bf16lo(v.y), aw = bf16hi(v.y);

    const int beg = row_ptr[g], end = row_ptr[g + 1];
    for (int j = beg; j < end; j += 8) {
        int   idx[8];
        float wt[8];
#pragma unroll
        for (int k = 0; k < 8; k++) {
            int jj = j + k;
            bool in = jj < end;
            idx[k] = in ? jj : (end - 1);
            wt[k] = in ? 1.f : 0.f;
        }
        int s[8];
#pragma unroll
        for (int k = 0; k < 8; k++) s[k] = col[idx[k]];
        uint2 u[8];
#pragma unroll
        for (int k = 0; k < 8; k++) u[k] = ts[(size_t)s[k] * 32 + c];
#pragma unroll
        for (int k = 0; k < 8; k++) {
            ax = fmaf(wt[k], bf16lo(u[k].x), ax);
            ay = fmaf(wt[k], bf16hi(u[k].x), ay);
            az = fmaf(wt[k], bf16lo(u[k].y), az);
            aw = fmaf(wt[k], bf16hi(u[k].y), aw);
        }
    }
    float dm = dinv[g];
    float4 b = ((const float4*)bias)[c];
    float4 o;
    o.x = fmaxf(fmaf(dm, ax, b.x), 0.f);
    o.y = fmaxf(fmaf(dm, ay, b.y), 0.f);
    o.z = fmaxf(fmaf(dm, az, b.z), 0.f);
    o.w = fmaxf(fmaf(dm, aw, b.w), 0.f);
    ((float4*)out)[(size_t)g * 32 + c] = o;
}

// ---------------- MFMA bf16 GEMM: D[m][n] = sum_k X[m][k]*W[n][k]  (N=128) ----------------
// MODE 1: out = bf16(relu(acc + bias[n]));  MODE 2: out = bf16(dinv[m]*acc)

template<int K, int MODE>
__global__ __launch_bounds__(256) void k_gemm_mfma(const unsigned* __restrict__ Xb,
                                                   const unsigned* __restrict__ Wb,
                                                   const float* __restrict__ bias,
                                                   const float* __restrict__ dinv,
                                                   unsigned short* __restrict__ Ob) {
    constexpr int KU  = K / 2;
    constexpr int SP  = K + 8;
    constexpr int SPU = SP / 2;
    __shared__ __align__(16) unsigned As_u[64 * SPU];
    __shared__ __align__(16) unsigned Bs_u[128 * SPU];

    const int tid = threadIdx.x;
    const int bm = blockIdx.x * 64;

    for (int i = tid; i < 64 * KU; i += 256) {
        int r = i / KU, c = i % KU;
        int m = bm + r;
        As_u[r * SPU + c] = (m < N_NODES) ? Xb[(size_t)m * KU + c] : 0u;
    }
    for (int i = tid; i < 128 * KU; i += 256) {
        int r = i / KU, c = i % KU;
        Bs_u[r * SPU + c] = Wb[r * KU + c];
    }
    __syncthreads();

    const int wv = tid >> 6;
    const int lane = tid & 63;
    const int lr = lane & 15;
    const int q = lane >> 4;

    f32x4 acc[8];
#pragma unroll
    for (int nt = 0; nt < 8; nt++) acc[nt] = (f32x4){0.f, 0.f, 0.f, 0.f};

    const short* As_s = (const short*)As_u;
    const short* Bs_s = (const short*)Bs_u;
#pragma unroll
    for (int k0 = 0; k0 < K; k0 += 32) {
        bf16x8 a = *(const bf16x8*)(As_s + (wv * 16 + lr) * SP + k0 + q * 8);
#pragma unroll
        for (int nt = 0; nt < 8; nt++) {
            bf16x8 b = *(const bf16x8*)(Bs_s + (nt * 16 + lr) * SP + k0 + q * 8);
            acc[nt] = __builtin_amdgcn_mfma_f32_16x16x32_bf16(a, b, acc[nt], 0, 0, 0);
        }
    }

#pragma unroll
    for (int nt = 0; nt < 8; nt++) {
        int cN = nt * 16 + lr;
        float bv = (MODE == 1) ? bias[cN] : 0.f;
#pragma unroll
        for (int i = 0; i < 4; i++) {
            int m = bm + wv * 16 + q * 4 + i;
            if (m < N_NODES) {
                float v = acc[nt][i];
                if (MODE == 1) v = fmaxf(v + bv, 0.f);
                else           v = dinv[m] * v;
                Ob[(size_t)m * HID_DIM + cN] = bf16r(v);
            }
        }
    }
}

// ---------------- fused mean-pool + FC head ----------------

__global__ __launch_bounds__(256) void k_pool_fc(const float* __restrict__ h,
                                                 const int* __restrict__ gstart,
                                                 const float* __restrict__ fcw,
                                                 const float* __restrict__ fcb,
                                                 float* __restrict__ out) {
    const int g = blockIdx.x;
    const int f = threadIdx.x & 127;
    const int s = threadIdx.x >> 7;        // 0 or 1
    const int beg = gstart[g], end = gstart[g + 1];

    float acc = 0.f;
#pragma unroll 4
    for (int m = beg + s; m < end; m += 2)
        acc += h[(size_t)m * HID_DIM + f];

    __shared__ float tmp[256];
    __shared__ float pool[HID_DIM];
    tmp[threadIdx.x] = acc;
    __syncthreads();
    if (s == 0) {
        float tot = tmp[f] + tmp[128 + f];
        float c = fmaxf((float)(end - beg), 1.f);
        pool[f] = tot / c;
    }
    __syncthreads();
    if (threadIdx.x < OUT_DIM) {
        float a = fcb[threadIdx.x];
#pragma unroll 8
        for (int k = 0; k < HID_DIM; k++)
            a = fmaf(pool[k], fcw[threadIdx.x * HID_DIM + k], a);
        out[g * OUT_DIM + threadIdx.x] = a;
    }
}

// ---------------- launch ----------------

extern "C" void kernel_launch(void* const* d_in, const int* in_sizes, int n_in,
                              void* d_out, int out_size, void* d_ws, size_t ws_size,
                              hipStream_t stream) {
    const float* x   = (const float*)d_in[0];
    const int*  eidx = (const int*)d_in[1];
    const int* batch = (const int*)d_in[2];
    const float* w1  = (const float*)d_in[3];
    const float* b1  = (const float*)d_in[4];
    const float* w2  = (const float*)d_in[5];
    const float* b2  = (const float*)d_in[6];
    const float* fcw = (const float*)d_in[7];
    const float* fcb = (const float*)d_in[8];
    float* out = (float*)d_out;
    const int* src = eidx;             // edge_index[0]
    const int* dst = eidx + N_EDGES;   // edge_index[1]

    char* w = (char*)d_ws;
    unsigned* xs   = (unsigned*)(w);                  // 6,400,000 B
    unsigned* aggb = (unsigned*)(w + 6400000);        // 6,400,000 B
    uint2*    ts2  = (uint2*)(w);                     // 12,800,000 B (reuse of region A)
    unsigned short* h1b = (unsigned short*)(w + 12800000);  // 12,800,000 B
    float* bufB    = (float*)(w + 25600000);          // 25,600,000 B (out2 fp32, late)
    unsigned* ebuf = (unsigned*)(w + 25600000);       // 3,200,000 B (CSR build, early — reuses bufB)
    int*   row_ptr = (int*)  (w + 51200000);          // 200,064 B
    float* dinv    = (float*)(w + 51400064);          // 200,000 B
    unsigned short* col = (unsigned short*)(w + 51600064);  // 1,600,000 B (u16)
    int*   hpart   = (int*)  (w + 53200064);          // 153,664 B (196*196)
    int*   gbase   = (int*)  (w + 53353728);          // 788 B (197 ints)
    int*   gcur    = (int*)  (w + 53354516);          // 784 B
    int*   gstart  = (int*)  (w + 53355300);          // 260 B
    unsigned* w1b  = (unsigned*)(w + 53355584);       // 16,384 B
    unsigned* w2b  = (unsigned*)(w + 53371968);       // 32,768 B (end ~53.4 MB)

    dim3 b256(256);

    // CSR build (counting sort; graph static across both layers) + fused bounds/wpack/xscale
    k_hist <<<dim3(NBUCK), b256, 0, stream>>>(dst, batch, w1, w2, hpart, gstart, w1b, w2b);
    k_bscan<<<dim3(1), b256, 0, stream>>>(hpart, gbase, gcur);
    k_fill1<<<dim3(NBUCK), b256, 0, stream>>>(src, dst, gcur, ebuf);
    k_fill2<<<dim3(NBUCK), b256, 0, stream>>>(ebuf, gbase, x, row_ptr, dinv, col, xs);

    // layer 1 (aggregate-then-transform, all-bf16 payloads):
    k_gather64<<<dim3(N_NODES / 8), b256, 0, stream>>>(xs, row_ptr, col, dinv, aggb);
    k_gemm_mfma<IN_DIM, 1><<<dim3((N_NODES + 63) / 64), b256, 0, stream>>>(aggb, w1b, b1, dinv, h1b);

    // layer 2 (transform-then-aggregate):
    k_gemm_mfma<HID_DIM, 2><<<dim3((N_NODES + 63) / 64), b256, 0, stream>>>((const unsigned*)h1b, w2b, b1, dinv, (unsigned short*)ts2);
    k_gather128<<<dim3(N_NODES / 8), b256, 0, stream>>>(ts2, row_ptr, col, dinv, b2, bufB);

    // fused mean-pool + FC head
    k_pool_fc<<<dim3(N_GRAPHS), b256, 0, stream>>>(bufB, gstart, fcw, fcb, out);
}